// Round 11
// baseline (414.931 us; speedup 1.0000x reference)
//
#include <hip/hip_runtime.h>

// CTC forward loss (sum, zero_infinity), B=32, T=1024, V=1024, L=256, S=513.
//
// Pass 1 (ctc_gather): per (b,t) row — coalesced row copy into LDS via
//   global_load_lds DMA (R13/R14/R16-proven), then 257 probs gathered from
//   LDS. Compact output (stride 256) to workspace; in-place fallback.
//
// Pass 2 (ctc_dp): R19/R20 = single-wave zero-sync structure. Toolchain
//   rule (R17/R18 evidence): 128-bit vector values as inline-asm INPUTS
//   ("v"(float4)) are unsupported ("indirect register inputs"); 128-bit
//   OUTPUTS ("=&v"(float4)) are fine. So: all LOADS are asm-pinned (named
//   float4 scalar outputs — never array elements, which become
//   alloca/memory operands); all LDS WRITES are plain float4 stores
//   bracketed by asm memory-clobber barriers (vmcnt(0)+SB before: data
//   ready, stores can't hoist; lgkmcnt(0)+SB after: drained before next
//   iter's asm ds_reads). R16's producer used exactly this store pattern.
//   Per iter c: 16x asm global_load_dwordx4 (chunk c+1, full-chunk lead)
//   -> asm ds_read_b128 x12 (rows 0-7 + blanks) -> lgkm(0) -> steps 0-7
//   -> asm ds_read x8 (rows 8-15) -> lgkm(0) -> steps 8-15
//   -> vmcnt(0) (free: ~1000cyc since issue) -> 16x plain float4 LDS
//   stores (chunk c+1 -> alt slot) -> lgkm(0).
//   Ablation ledger: R9/R13 DMA-staged=107/108 (253cyc/op DMA issue
//   serialization), R12 reg-pipeline=146 (sunk), R14/R16 producer
//   waves=110/121 (spin/LDS contention). This build: zero sync, zero DMA,
//   zero spin, nothing compiler-schedulable in the data path.
//   Numerics bit-identical to R9-R16 (pass, absmax 1024).
//   (R20 = R19 resubmitted verbatim: R19 died on GPU acquisition timeout
//    before running — no measurement was taken.)

constexpr int B_ = 32, T_ = 1024, V_ = 1024, L_ = 256;
constexpr int CH = 16;           // steps per chunk
constexpr int NCHUNK = 64;       // 64*16 slots cover t = 1..1023 (+1 pad)
constexpr float LN2F = 0.6931471805599453f;

typedef const __attribute__((address_space(1))) unsigned int* gp_t;
typedef __attribute__((address_space(3))) unsigned int* lp_t;

template <int CTRL>
__device__ __forceinline__ float dpp_fmax(float x) {
    const int t = __builtin_amdgcn_update_dpp(0, __float_as_int(x), CTRL, 0xf, 0xf, true);
    return fmaxf(x, __int_as_float(t));
}

__device__ __forceinline__ float wave_max_dpp(float x) {
    x = dpp_fmax<0x111>(x);   // row_shr:1
    x = dpp_fmax<0x112>(x);   // row_shr:2
    x = dpp_fmax<0x114>(x);   // row_shr:4
    x = dpp_fmax<0x118>(x);   // row_shr:8
    x = dpp_fmax<0x142>(x);   // row_bcast:15
    x = dpp_fmax<0x143>(x);   // row_bcast:31
    return __int_as_float(__builtin_amdgcn_readlane(__float_as_int(x), 63));
}

__device__ __forceinline__ float dpp_wave_shr1(float x) {
    return __int_as_float(
        __builtin_amdgcn_update_dpp(0, __float_as_int(x), 0x138, 0xf, 0xf, true));
}

__global__ __launch_bounds__(256, 8) void ctc_gather(
    const float* __restrict__ lp, float* __restrict__ qdst, int qstride,
    const int* __restrict__ labels, float* __restrict__ blanks)
{
    __shared__ float srow[4][V_];              // 16 KB: one row per wave
    const int wave = threadIdx.x >> 6;
    const int lane = threadIdx.x & 63;
    const int r = blockIdx.x * 4 + wave;       // row in [0, B*T)
    const int b = r >> 10;                     // T = 1024
    const float* row = lp + (size_t)r * V_;
    float* orow = qdst + (size_t)r * qstride;
    const int* labb = labels + b * L_;

    #pragma unroll
    for (int j = 0; j < 4; ++j)
        __builtin_amdgcn_global_load_lds((gp_t)(row + 256 * j + 4 * lane),
                                         (lp_t)&srow[wave][256 * j], 16, 0, 0);
    const int4 e = *(const int4*)(labb + 4 * lane);
    asm volatile("s_waitcnt vmcnt(0)" ::: "memory");  // row fully in LDS
                                                      // (WAR-safe in-place)
    __builtin_amdgcn_sched_barrier(0);
    const float v0 = srow[wave][e.x];
    const float v1 = srow[wave][e.y];
    const float v2 = srow[wave][e.z];
    const float v3 = srow[wave][e.w];
    const float vb = srow[wave][0];
    float4 q;
    q.x = __expf(v0); q.y = __expf(v1); q.z = __expf(v2); q.w = __expf(v3);
    const float qb = __expf(vb);
    *(float4*)(orow + 4 * lane) = q;           // cols 4l..4l+3 (compact)
    if (lane == 0) {
        const int t = r & (T_ - 1);
        blanks[(r & ~(T_ - 1)) + ((t + T_ - 1) & (T_ - 1))] = qb;  // shifted
    }
}

// asm helpers: float4 OUTPUTS only (inputs of float4 are not supported)
#define GL16(dst, t_expr)                                                   \
    { int t_ = (t_expr); if (t_ > T_ - 1) t_ = T_ - 1;                      \
      const float* p_ = Qb + (size_t)t_ * qstride + 4 * lane;               \
      asm volatile("global_load_dwordx4 %0, %1, off"                        \
                   : "=&v"(dst) : "v"(p_)); }
#define DSR(dst, addr)                                                      \
    asm volatile("ds_read_b128 %0, %1" : "=&v"(dst) : "v"(addr))

__global__ __launch_bounds__(64, 1) void ctc_dp(
    const float* __restrict__ Q, int qstride,
    const float* __restrict__ blanks, const int* __restrict__ labels,
    const int* __restrict__ input_lens, const int* __restrict__ label_lens,
    float* __restrict__ out)
{
    __shared__ float blk[T_];                  // shifted blank probs (4 KB)
    __shared__ float buf[2][CH][256];          // double buffer (32 KB)
    const int b    = blockIdx.x;
    const int lane = threadIdx.x & 63;
    const float* Qb  = Q + (size_t)b * T_ * qstride;
    const float* blg = blanks + b * T_;
    const int*  labb = labels + b * L_;
    const int il = input_lens[b];
    const int ll = label_lens[b];
    const int tend = il < T_ ? il : T_;

    // blanks -> LDS via DMA, once (covered by prologue vmcnt(0))
    #pragma unroll
    for (int i = 0; i < 4; ++i)
        __builtin_amdgcn_global_load_lds((gp_t)(blg + 256 * i + 4 * lane),
                                         (lp_t)&blk[256 * i], 16, 0, 0);

    const int4 e  = *(const int4*)(labb + 4 * lane);
    const int  ep = (lane > 0) ? labb[4 * lane - 1] : -1;
    const float kf0 = ((8 * lane + 1) >= 3 && e.x != ep) ? 1.f : 0.f;
    const float kf1 = (e.y != e.x) ? 1.f : 0.f;
    const float kf2 = (e.z != e.y) ? 1.f : 0.f;
    const float kf3 = (e.w != e.z) ? 1.f : 0.f;
    const float bl0 = blg[T_ - 1];             // blank(t=0), shifted slot
    const float q00 = Qb[0];                   // label-state-1 prob at t=0
    float p0 = (lane == 0) ? bl0 : 0.f;
    float p1 = (lane == 0) ? q00 : 0.f;
    float p2 = 0.f, p3 = 0.f, p4 = 0.f, p5 = 0.f,
          p6 = 0.f, p7 = 0.f, p8 = 0.f;
    int Esc = 0;        // true alpha = stored * 2^{-Esc}
    float pm1 = 0.f;    // alpha[8l-1] entering next step
    float sfP = 1.f, sfM = 1.f;                // pending deferred scales

    const unsigned bufb = (unsigned)(size_t)(lp_t)&buf[0][0][0];
    const unsigned blkb = (unsigned)(size_t)(lp_t)&blk[0];
    const unsigned lane16 = (unsigned)lane * 16u;

    auto snap = [&]() -> float {
        float m = fmaxf(fmaxf(fmaxf(fmaxf(p0, p1), fmaxf(p2, p3)),
                              fmaxf(fmaxf(p4, p5), fmaxf(p6, p7))), p8);
        m = wave_max_dpp(m);
        const unsigned eb = (__float_as_uint(m) >> 23) & 0xffu;
        if (eb >= 1u && eb <= 254u) {
            unsigned k = 318u - eb;            // biased exp of 2^(64-(eb-127))
            if (k > 254u) k = 254u;
            Esc += (int)k - 127;
            return __uint_as_float(k << 23);   // exact 2^(k-127)
        }
        return 1.f;
    };

    // named asm output buffers (NEVER arrays — R17 post-mortem)
    float4 r0, r1, r2, r3, r4, r5, r6, r7,
           r8, r9, r10, r11, r12, r13, r14, r15;
    float4 qv0, qv1, qv2, qv3, qv4, qv5, qv6, qv7;
    float4 bb0, bb1, bb2, bb3;

    // plain-store helper (compiler emits ds_write_b128; ordering is pinned
    // by the surrounding asm memory-clobber barriers)
#define STORE_CHUNK(slot_)                                                  \
    {                                                                       \
        float* wb_ = &buf[(slot_)][0][0] + 4 * lane;                        \
        *(float4*)(wb_ + 0 * 256)  = r0;  *(float4*)(wb_ + 1 * 256)  = r1;  \
        *(float4*)(wb_ + 2 * 256)  = r2;  *(float4*)(wb_ + 3 * 256)  = r3;  \
        *(float4*)(wb_ + 4 * 256)  = r4;  *(float4*)(wb_ + 5 * 256)  = r5;  \
        *(float4*)(wb_ + 6 * 256)  = r6;  *(float4*)(wb_ + 7 * 256)  = r7;  \
        *(float4*)(wb_ + 8 * 256)  = r8;  *(float4*)(wb_ + 9 * 256)  = r9;  \
        *(float4*)(wb_ + 10 * 256) = r10; *(float4*)(wb_ + 11 * 256) = r11; \
        *(float4*)(wb_ + 12 * 256) = r12; *(float4*)(wb_ + 13 * 256) = r13; \
        *(float4*)(wb_ + 14 * 256) = r14; *(float4*)(wb_ + 15 * 256) = r15; \
    }

    // ---- prologue: chunk 0 -> regs -> slot 0 ----
    GL16(r0, 1);  GL16(r1, 2);  GL16(r2, 3);  GL16(r3, 4);
    GL16(r4, 5);  GL16(r5, 6);  GL16(r6, 7);  GL16(r7, 8);
    GL16(r8, 9);  GL16(r9, 10); GL16(r10, 11); GL16(r11, 12);
    GL16(r12, 13); GL16(r13, 14); GL16(r14, 15); GL16(r15, 16);
    asm volatile("s_waitcnt vmcnt(0)" ::: "memory");   // blk DMA + r*
    __builtin_amdgcn_sched_barrier(0);
    STORE_CHUNK(0);
    asm volatile("s_waitcnt lgkmcnt(0)" ::: "memory");
    __builtin_amdgcn_sched_barrier(0);

#define DP_STEP(ii, qvec)                                                   \
    {                                                                       \
        float4 q = (qvec);                                                  \
        const float4 f4 = ((ii) >> 2) == 0 ? bb0 : ((ii) >> 2) == 1 ? bb1   \
                        : ((ii) >> 2) == 2 ? bb2 : bb3;                     \
        const int g = (ii) & 3;                                             \
        float qb = (g == 0) ? f4.x : (g == 1) ? f4.y                        \
                 : (g == 2) ? f4.z : f4.w;                                  \
        if ((ii) == 0) { q.x *= sfP; q.y *= sfP; q.z *= sfP; q.w *= sfP;    \
                         qb *= sfP; }                                       \
        if ((ii) == 8) { q.x *= sfM; q.y *= sfM; q.z *= sfM; q.w *= sfM;    \
                         qb *= sfM; }                                       \
        const int t = 1 + c * CH + (ii);                                    \
        if (t < tend) {                                                     \
            const float n7 = fmaf(kf3, p5, p7 + p6) * q.w;                  \
            const float n8 = (p8 + p7) * qb;                                \
            const float pm1n = dpp_wave_shr1(n7);                           \
            const float n0 = (p0 + pm1) * qb;                               \
            const float n1 = fmaf(kf0, pm1, p1 + p0) * q.x;                 \
            const float n2 = (p2 + p1) * qb;                                \
            const float n3 = fmaf(kf1, p1, p3 + p2) * q.y;                  \
            const float n4 = (p4 + p3) * qb;                                \
            const float n5 = fmaf(kf2, p3, p5 + p4) * q.z;                  \
            const float n6 = (p6 + p5) * qb;                                \
            p0 = n0; p1 = n1; p2 = n2; p3 = n3; p4 = n4;                    \
            p5 = n5; p6 = n6; p7 = n7; p8 = n8; pm1 = pm1n;                 \
        }                                                                   \
        if ((ii) == 4)  sfM = snap();                                       \
        if ((ii) == 12) sfP = snap();                                       \
    }

    for (int c = 0; c < NCHUNK; ++c) {
        const bool more = (c + 1 < NCHUNK);
        if (more) {                            // issue chunk c+1 early
            const int tb = 1 + (c + 1) * CH;
            GL16(r0, tb + 0);  GL16(r1, tb + 1);  GL16(r2, tb + 2);
            GL16(r3, tb + 3);  GL16(r4, tb + 4);  GL16(r5, tb + 5);
            GL16(r6, tb + 6);  GL16(r7, tb + 7);  GL16(r8, tb + 8);
            GL16(r9, tb + 9);  GL16(r10, tb + 10); GL16(r11, tb + 11);
            GL16(r12, tb + 12); GL16(r13, tb + 13); GL16(r14, tb + 14);
            GL16(r15, tb + 15);
        }
        const unsigned qa0 = bufb + ((unsigned)(c & 1) << 14) + lane16;
        DSR(qv0, qa0 + 0u * 1024u); DSR(qv1, qa0 + 1u * 1024u);
        DSR(qv2, qa0 + 2u * 1024u); DSR(qv3, qa0 + 3u * 1024u);
        DSR(qv4, qa0 + 4u * 1024u); DSR(qv5, qa0 + 5u * 1024u);
        DSR(qv6, qa0 + 6u * 1024u); DSR(qv7, qa0 + 7u * 1024u);
        const unsigned ba0 = blkb + (unsigned)c * 64u;
        DSR(bb0, ba0 + 0u); DSR(bb1, ba0 + 16u);
        DSR(bb2, ba0 + 32u); DSR(bb3, ba0 + 48u);
        asm volatile("s_waitcnt lgkmcnt(0)" ::: "memory");
        __builtin_amdgcn_sched_barrier(0);

        DP_STEP(0, qv0) DP_STEP(1, qv1) DP_STEP(2, qv2) DP_STEP(3, qv3)
        DP_STEP(4, qv4) DP_STEP(5, qv5) DP_STEP(6, qv6) DP_STEP(7, qv7)

        DSR(qv0, qa0 + 8u * 1024u);  DSR(qv1, qa0 + 9u * 1024u);
        DSR(qv2, qa0 + 10u * 1024u); DSR(qv3, qa0 + 11u * 1024u);
        DSR(qv4, qa0 + 12u * 1024u); DSR(qv5, qa0 + 13u * 1024u);
        DSR(qv6, qa0 + 14u * 1024u); DSR(qv7, qa0 + 15u * 1024u);
        asm volatile("s_waitcnt lgkmcnt(0)" ::: "memory");
        __builtin_amdgcn_sched_barrier(0);

        DP_STEP(8, qv0)  DP_STEP(9, qv1)  DP_STEP(10, qv2) DP_STEP(11, qv3)
        DP_STEP(12, qv4) DP_STEP(13, qv5) DP_STEP(14, qv6) DP_STEP(15, qv7)

        if (more) {                            // chunk c+1 regs -> alt slot
            asm volatile("s_waitcnt vmcnt(0)" ::: "memory");  // ~free now
            __builtin_amdgcn_sched_barrier(0);
            STORE_CHUNK((c + 1) & 1);
            asm volatile("s_waitcnt lgkmcnt(0)" ::: "memory");
            __builtin_amdgcn_sched_barrier(0);
        }
    }
#undef DP_STEP
#undef STORE_CHUNK

    // apply the last pending scale (its Esc contribution is counted)
    p0 *= sfP; p1 *= sfP; p2 *= sfP; p3 *= sfP; p4 *= sfP;
    p5 *= sfP; p6 *= sfP; p7 *= sfP; p8 *= sfP;

    // epilogue via shuffles only (once — latency irrelevant)
    const int sl = 2 * ll;                     // uniform
    auto pick = [&](int s) -> float {          // s uniform, 1..512
        if (s == 512) return __shfl(p8, 63);
        const int r = s & 7;
        float v = p0;
        v = (r == 1) ? p1 : v; v = (r == 2) ? p2 : v;
        v = (r == 3) ? p3 : v; v = (r == 4) ? p4 : v;
        v = (r == 5) ? p5 : v; v = (r == 6) ? p6 : v;
        v = (r == 7) ? p7 : v;
        return __shfl(v, s >> 3);
    };
    const float la = pick(sl);
    const float lb = pick(sl - 1);
    if (lane == 0) {
        const float tot = la + lb;
        float loss = (float)Esc * LN2F - __logf(tot);
        if (!(loss <= 1e29f)) loss = 0.f;      // zero_infinity
        atomicAdd(out, loss);
    }
}

extern "C" void kernel_launch(void* const* d_in, const int* in_sizes, int n_in,
                              void* d_out, int out_size, void* d_ws, size_t ws_size,
                              hipStream_t stream) {
    float*       lp     = (float*)d_in[0];
    const int*   labels = (const int*)d_in[1];
    const int*   il     = (const int*)d_in[2];
    const int*   ll     = (const int*)d_in[3];
    float* out    = (float*)d_out;
    float* blanks = (float*)d_ws;              // B*T floats = 128 KB

    // workspace layout: [blanks: B*T floats][Q': B*T*256 floats = 32 MB]
    const size_t need = (size_t)B_ * T_ * sizeof(float)
                      + (size_t)B_ * T_ * 256 * sizeof(float);
    const bool use_ws = ws_size >= need;
    float* qdst = use_ws ? (blanks + (size_t)B_ * T_) : lp;
    const int qstride = use_ws ? 256 : V_;     // compact rows in ws mode

    hipMemsetAsync(out, 0, sizeof(float), stream);   // d_out re-poisoned each replay
    ctc_gather<<<dim3(B_ * T_ / 4), dim3(256), 0, stream>>>(
        lp, qdst, qstride, labels, blanks);
    ctc_dp<<<dim3(B_), dim3(64), 0, stream>>>(
        qdst, qstride, blanks, labels, il, ll, out);
}